// Round 10
// baseline (371.807 us; speedup 1.0000x reference)
//
#include <hip/hip_runtime.h>

// SpanBasedChunker: semi-Markov CRF log-likelihood. B=32, L=1024, NS=32768, NG=64.
//
// Pipeline (all on `stream`):
//  1) memsetAsync: per-column hash keys+vals (+num) (32 MB)
//  2) scatter: XCD-localized hash-insert of s<=e span scores (dedup by s:
//     expm1(v1)+expm1(v2) != expm1(v1+v2)) + FUSED gold numerator (per-block
//     LDS hash of gold cells; partials linear in T -> atomicAdd num[b]).
//  3) prep: per column, compact hash -> 1KB record (uint2[128]):
//     [0]=(c,nr1) [1]=(nr2,nr3) [2..127]=far pairs (s, expm1(v)), t>=4.
//     ALL transcendentals here. Lane l's uint4 = rec[2l..2l+1].
//  4) dp: TWO chains per wave (R8 ran one chain/wave at ~420cyc/iter with
//     VALUBusy 1.2% -- stall-dominated across 3 different inner-loop shapes,
//     so AMORTIZE: lanes 0-31 = batch A, lanes 32-63 = batch B; every fixed
//     per-iteration cost is shared). LINEAR domain (x=e^{beta-m}, exact 2^-64
//     per-half rescale, branchless inside a rare wave-uniform branch):
//       x_i = P + K_i + nr1*x_{i-2} + nr2*x_{i-3} + nr3*x_{i-4} + c*x_{i-1}
//     K via per-half DPP sum (row_shr 1/2/4/8 + row_bcast:15) + bpermute
//     broadcast; gathers deferred 3 iters; 8-deep register load pipeline.
//  5) final: out = sum_b (num[b] - den[b])

#define B_   32
#define L_   1024
#define NS_  32768
#define NG_  64
#define CAP_ 128

#define DPP_ADD(v, ctrl) \
    ((v) + __int_as_float(__builtin_amdgcn_update_dpp( \
        0, __float_as_int(v), (ctrl), 0xf, 0xf, false)))

// per-half (32-lane) sum, result broadcast to every lane of its half
__device__ __forceinline__ float half_bcast_sum(float v, int lane) {
    v = DPP_ADD(v, 0x111);   // row_shr:1
    v = DPP_ADD(v, 0x112);   // row_shr:2
    v = DPP_ADD(v, 0x114);   // row_shr:4
    v = DPP_ADD(v, 0x118);   // row_shr:8   -> lane15/31/47/63 = row sums
    v = DPP_ADD(v, 0x142);   // row_bcast:15 -> lane31 = sumA, lane63 = sumB
    return __shfl(v, (lane & 32) + 31, 64);   // ds_bpermute broadcast per half
}

// ---------------------------------------------------------------- scatter (+gold)
__global__ void __launch_bounds__(256) sbc_scatter(
        const int2* __restrict__ spans, const float* __restrict__ scores,
        const int2* __restrict__ gold,  const int* __restrict__ labels,
        const float* __restrict__ gmask,
        unsigned int* __restrict__ keys, float* __restrict__ vals,
        float* __restrict__ num) {
    const int j = blockIdx.x;                  // 1024 blocks
    const int b = j & 31;                      // b%8 == j%8 -> XCD-local hash
    const int tid = threadIdx.x;
    __shared__ unsigned int hkey[128];
    __shared__ float hval[128];
    __shared__ int slotof[NG_];
    if (tid < 128) { hkey[tid] = 0u; hval[tid] = 0.f; }
    __syncthreads();
    if (tid < NG_) {                           // insert gold cells (64 into 128)
        int2 se = gold[b * NG_ + tid];
        unsigned cell = ((unsigned)se.x << 10) | (unsigned)se.y;
        unsigned key = cell + 1u;
        unsigned h = (cell * 2654435761u) >> 25;
        int slot = 0;
        for (int p = 0; p < 128; ++p) {        // bounded; empty slot exists
            unsigned old = atomicCAS(&hkey[h], 0u, key);
            if (old == 0u || old == key) { slot = (int)h; break; }
            h = (h + 1u) & 127u;
        }
        slotof[tid] = slot;
    }
    __syncthreads();
    #pragma unroll
    for (int r = 0; r < 4; ++r) {              // 4 spans per thread
        const int gi = (b << 15) + ((j >> 5) << 10) + (r << 8) + tid;
        int2 se = spans[gi];
        float sc = scores[gi];
        {   // gold probe (ALL spans, incl. s>e)
            unsigned cell = ((unsigned)se.x << 10) | (unsigned)se.y;
            unsigned key = cell + 1u;
            unsigned h = (cell * 2654435761u) >> 25;
            for (int p = 0; p < 128; ++p) {
                unsigned k = hkey[h];
                if (k == 0u) break;            // not a gold cell
                if (k == key) { atomicAdd(&hval[h], sc); break; }
                h = (h + 1u) & 127u;
            }
        }
        if (se.x <= se.y) {                    // DP only reads s<=e cells
            size_t col = ((size_t)b << 10) | (unsigned)se.y;
            unsigned int* kcol = keys + col * CAP_;
            float*        vcol = vals + col * CAP_;
            unsigned key = (unsigned)se.x + 1u;
            int h = se.x & (CAP_ - 1);
            for (int p = 0; p < CAP_; ++p) {   // bounded: never hangs
                unsigned old = atomicCAS(&kcol[h], 0u, key);
                if (old == 0u || old == key) { atomicAdd(&vcol[h], sc); break; }
                h = (h + 1) & (CAP_ - 1);
            }
        }
    }
    __syncthreads();
    if (tid < NG_) {                           // block-partial gold sum
        int g = b * NG_ + tid;
        float acc = hval[slotof[tid]] * gmask[g] * (2.f * (float)labels[g] - 1.f);
        #pragma unroll
        for (int o = 32; o; o >>= 1) acc += __shfl_xor(acc, o, 64);
        if (tid == 0) atomicAdd(&num[b], acc);
    }
}

// ---------------------------------------------------------------- prep
__global__ void __launch_bounds__(256) sbc_prep(const unsigned int* __restrict__ keys,
                                                const float* __restrict__ vals,
                                                uint2* __restrict__ rec) {
    const int j = blockIdx.x;
    const int b = j & 31;                      // XCD-local: reads scatter's L2
    const int cb = (j >> 5) * 16;              // 16 cols per block, 4 per wave
    const int wv = threadIdx.x >> 6;
    const int lane = threadIdx.x & 63;
    __shared__ uint2 st[4][CAP_];
    __shared__ float dnr[4][8];
    for (int cc = 0; cc < 4; ++cc) {
        const int e = cb + wv * 4 + cc;
        const size_t col = ((size_t)b << 10) | (unsigned)e;
        const unsigned int* kcol = keys + col * CAP_;
        const float*        vcol = vals + col * CAP_;
        ((uint4*)st[wv])[lane] = make_uint4(0u, 0u, 0u, 0u);   // zero-fill 1KB
        if (lane < 8) dnr[wv][lane] = 0.f;     // wave-private row: no barrier
        int cnt = 0;
        #pragma unroll
        for (int r = 0; r < 2; ++r) {
            int slot = lane + r * 64;
            unsigned k = kcol[slot];
            float v = vcol[slot];
            bool occ = (k != 0u);
            int s = (int)k - 1;
            int t = e - s;                     // >=0 (only s<=e inserted)
            if (occ && t <= 3) atomicAdd(&dnr[wv][t], v);
            bool far = occ && (t >= 4);
            unsigned long long mb = __ballot(far);
            int pos = cnt + (int)__popcll(mb & ((1ull << lane) - 1ull));
            if (far && pos < CAP_ - 2)
                st[wv][2 + pos] = make_uint2((unsigned)s, __float_as_uint(expm1f(v)));
            cnt += (int)__popcll(mb);
        }
        if (lane == 0) {
            float d = dnr[wv][0];
            st[wv][0] = make_uint2(__float_as_uint(__expf(d) + __expf(-d) - 1.f),
                                   __float_as_uint(expm1f(dnr[wv][1])));
            st[wv][1] = make_uint2(__float_as_uint(expm1f(dnr[wv][2])),
                                   __float_as_uint(expm1f(dnr[wv][3])));
        }
        // same-wave DS ordering; compiler inserts lgkmcnt before the read
        ((uint4*)(rec + col * CAP_))[lane] = ((const uint4*)st[wv])[lane];
    }
}

// ---------------------------------------------------------------- dp (2 chains/wave)
__global__ void __launch_bounds__(64) sbc_dp(const uint2* __restrict__ rec,
                                             const float* __restrict__ tmask,
                                             float* __restrict__ den) {
    const int lane = threadIdx.x;
    const int sl   = lane & 31;
    const int half = lane >> 5;
    // batch pair chosen so both batches' rec panels are L2-local to this XCD:
    // bA=(bid&7)+16*(bid>>3), bB=bA+8  (covers 0..31 over 16 blocks)
    const int batch = (blockIdx.x & 7) + ((blockIdx.x >> 3) << 4) + (half << 3);
    __shared__ float xs2[2][L_ + 1];
    float* xsh = xs2[half];
    const uint4* pb = (const uint4*)rec + (size_t)batch * L_ * 64;

    // zero-init: junk-address reads (meta lane, w=0 slots) must not see NaN
    for (int t = sl; t <= L_; t += 32) xsh[t] = 0.f;
    if (sl == 0) xsh[0] = 1.f;                 // x_0 = e^{beta_0} = 1

    float tm = 0.f;
    for (int t = sl; t < L_; t += 32) tm += tmask[batch * L_ + t];
    tm = half_bcast_sum(tm, lane);
    int n = (int)(tm + 0.5f);
    n = (n > L_) ? L_ : n;

    // metaS[c&3]: col c's slot-0 uint4 (c,nr1,nr2,nr3) — valid at sl==0.
    // pkS0/1[c&7]: col c's two per-lane uint4 (slots sl and 32+sl), loaded
    //              8 iterations ahead of the gather.
    uint4 metaS[4];
    #pragma unroll
    for (int c = 0; c < 4; ++c) metaS[c] = pb[c * 64 + sl];   // cols 0..3
    uint4 pkS0[8], pkS1[8];
    #pragma unroll
    for (int k = 0; k < 8; ++k) {              // cols 4..11
        pkS0[(4 + k) & 7] = pb[(4 + k) * 64 + sl];
        pkS1[(4 + k) & 7] = pb[(4 + k) * 64 + 32 + sl];
    }

    // deferred-gather stages (consumed 3 iterations after issue)
    float gX0[4]={0,0,0,0}, gX1[4]={0,0,0,0}, gX2[4]={0,0,0,0}, gX3[4]={0,0,0,0};
    float gW0[4]={0,0,0,0}, gW1[4]={0,0,0,0}, gW2[4]={0,0,0,0}, gW3[4]={0,0,0,0};
    float Kcur = 0.f;                          // K(col e), per-half
    float P = 1.f, m = 0.f;                    // valid at sl==0
    float xm1 = 1.f, xm2 = 0.f, xm3 = 0.f, xm4 = 0.f;
    const bool gl = (sl >= 1);                 // slot 0 of uint4#1 is meta

    for (int ii = 0; ii < L_; ii += 8) {
        #pragma unroll
        for (int Kc = 0; Kc < 8; ++Kc) {
            const int e = ii + Kc;
            // consume gather from iter e-3 (col e+1)
            const int cs = (Kc + 1) & 3;
            float p = gW0[cs]*gX0[cs] + gW1[cs]*gX1[cs]
                    + gW2[cs]*gX2[cs] + gW3[cs]*gX3[cs];
            float Knext = half_bcast_sum(p, lane);   // K(col e+1), per-half
            uint4 M = metaS[Kc & 3];           // col e meta
            // gather col e+4 (far pairs s <= e; xs filled through e)
            uint4 pk0 = pkS0[(Kc + 4) & 7];
            uint4 pk1 = pkS1[(Kc + 4) & 7];
            metaS[Kc & 3] = pk0;               // col e+4 meta for iter e+4
            gX0[Kc & 3] = xsh[(int)(pk0.x & 1023u)];
            gX1[Kc & 3] = xsh[(int)(pk0.z & 1023u)];
            gX2[Kc & 3] = xsh[(int)(pk1.x & 1023u)];
            gX3[Kc & 3] = xsh[(int)(pk1.z & 1023u)];
            gW0[Kc & 3] = gl ? __uint_as_float(pk0.y) : 0.f;
            gW1[Kc & 3] = gl ? __uint_as_float(pk0.w) : 0.f;
            gW2[Kc & 3] = __uint_as_float(pk1.y);
            gW3[Kc & 3] = __uint_as_float(pk1.w);
            // refill with col e+12 (clamped dup at tail: never consumed)
            int cl = e + 12; cl = (cl > L_ - 1) ? (L_ - 1) : cl;
            pkS0[(Kc + 4) & 7] = pb[cl * 64 + sl];
            pkS1[(Kc + 4) & 7] = pb[cl * 64 + 32 + sl];
            // serial chain, SIMT on lanes 0 and 32: coeff(x_{i-1}) = 1(in P)+c
            float A = (P + Kcur)
                    + (__uint_as_float(M.y) * xm2 + __uint_as_float(M.z) * xm3)
                    + __uint_as_float(M.w) * xm4;
            float x = fmaf(xm1, __uint_as_float(M.x), A);
            if (sl == 0) xsh[e + 1] = x;       // one ds_write, both halves
            P += x;
            // rescale: wave-uniform branch on either half's lane-0 predicate;
            // inside, branchless per-half scale (exact powers of two)
            unsigned long long bm = __ballot(x > 0x1p64f);
            if (bm & 0x100000001ull) {
                unsigned nb = (unsigned)(bm >> (lane & 32)) & 1u;
                float s_ = nb ? 0x1p-64f : 1.f;
                x *= s_; xm1 *= s_; xm2 *= s_; xm3 *= s_;
                P *= s_; Knext *= s_;
                #pragma unroll
                for (int q = 0; q < 4; ++q) {
                    gX0[q]*=s_; gX1[q]*=s_; gX2[q]*=s_; gX3[q]*=s_;
                }
                m += nb ? 44.361419555836498f : 0.f;   // 64*ln2
                for (int jj = sl; jj <= e + 1; jj += 32) xsh[jj] *= s_;
            }
            xm4 = xm3; xm3 = xm2; xm2 = xm1; xm1 = x;
            Kcur = Knext;
        }
    }
    if (sl == 0) den[batch] = m + logf(xsh[n]);
}

// ---------------------------------------------------------------- final
__global__ void sbc_final(const float* __restrict__ num,
                          const float* __restrict__ den,
                          float* __restrict__ out) {
    int lane = threadIdx.x;
    float v = (lane < B_) ? (num[lane] - den[lane]) : 0.f;
    #pragma unroll
    for (int o = 32; o; o >>= 1) v += __shfl_xor(v, o, 64);
    if (lane == 0) out[0] = v;
}

// ---------------------------------------------------------------- launch
extern "C" void kernel_launch(void* const* d_in, const int* in_sizes, int n_in,
                              void* d_out, int out_size, void* d_ws, size_t ws_size,
                              hipStream_t stream) {
    const int2*  spans       = (const int2*)d_in[0];
    const float* span_scores = (const float*)d_in[1];
    const int2*  gold        = (const int2*)d_in[2];
    const int*   glabels     = (const int*)d_in[3];
    // d_in[4] = span_mask: accepted but unused by the reference math
    const float* gmask       = (const float*)d_in[5];
    const float* tmask       = (const float*)d_in[6];
    float* out = (float*)d_out;
    (void)in_sizes; (void)n_in; (void)out_size; (void)ws_size;

    char* ws = (char*)d_ws;
    const size_t keysB = (size_t)B_ * L_ * CAP_ * 4;   // 16 MB
    const size_t valsB = keysB;                        // 16 MB
    unsigned int* keys = (unsigned int*)(ws);
    float*        vals = (float*)(ws + keysB);
    float*        num  = (float*)(ws + keysB + valsB);             // 128 B
    float*        den  = num + B_;                                 // 128 B
    uint2*        recp = (uint2*)(ws + keysB + valsB + 256);       // 32 MB

    // keys+vals+num contiguous: one memset zeroes the hash AND the gold accum
    hipMemsetAsync(keys, 0, keysB + valsB + B_ * 4, stream);
    sbc_scatter<<<1024, 256, 0, stream>>>(spans, span_scores, gold, glabels,
                                          gmask, keys, vals, num);
    sbc_prep<<<2048, 256, 0, stream>>>(keys, vals, recp);
    sbc_dp<<<16, 64, 0, stream>>>(recp, tmask, den);
    sbc_final<<<1, 64, 0, stream>>>(num, den, out);
}